// Round 8
// baseline (61.501 us; speedup 1.0000x reference)
//
#include <hip/hip_runtime.h>
#include <math.h>

#define PI_F 3.14159265358979323846f
typedef float floatx4 __attribute__((ext_vector_type(4)));

// Kernel 1: Zernike pooling. One block per batch image b: 256 px x 96 ch = 96KB
// CONTIGUOUS. 384 threads; chunk n = 384*j + t  (j=0..15) -> every wave-instr
// loads 64 consecutive float4 = 1KB contiguous (m13 streaming pattern).
// 384 % 24 == 0  =>  thread owns fixed chunk-column c = t%24 (4 channels) and
// fixed pixel-column q = t/24  =>  X is thread-constant, Y = lin[j].
// Cross-q (16-way) reductions via two small LDS rounds.
__global__ __launch_bounds__(384, 3) void zpool_kernel(const float* __restrict__ x,
                                                       float* __restrict__ pooled) {
  const int b = blockIdx.x;
  const int t = threadIdx.x;        // 0..383
  const int c = t % 24;             // float4-chunk column = 4 channels
  const int q = t / 24;             // pixel x (col) 0..15
  const float X = -1.0f + (float)q * (2.0f / 15.0f);
  const float* __restrict__ src = x + (size_t)b * 24576;

  __shared__ float lds[16 * 960 + 960];   // 63.75 KB: partials + reduced row
  float* red2 = &lds[16 * 960];           // 960 floats

  // Load whole image to registers: 16 x float4 per thread, fully coalesced.
  floatx4 f[16];
#pragma unroll
  for (int j = 0; j < 16; ++j)
    f[j] = *reinterpret_cast<const floatx4*>(src + (size_t)(384 * j + t) * 4);

  // Pass 1: centroid partials. X thread-constant -> sx = X * s0.
  floatx4 s0 = {0, 0, 0, 0}, sy = {0, 0, 0, 0};
#pragma unroll
  for (int j = 0; j < 16; ++j) {
    const float Y = -1.0f + (float)j * (2.0f / 15.0f);
    s0 += f[j];
    sy += f[j] * Y;
  }
  const floatx4 sx = s0 * X;
  {
    float* wp = &lds[q * 288 + c * 12];
    *reinterpret_cast<floatx4*>(wp + 0) = s0;
    *reinterpret_cast<floatx4*>(wp + 4) = sx;
    *reinterpret_cast<floatx4*>(wp + 8) = sy;
  }
  __syncthreads();
  if (t < 288) {                     // reduce 288 words over 16 q
    float S = 0.f;
#pragma unroll
    for (int qq = 0; qq < 16; ++qq) S += lds[qq * 288 + t];
    red2[t] = S;
  }
  __syncthreads();
  const floatx4 S0 = *reinterpret_cast<floatx4*>(&red2[c * 12]);
  const floatx4 SX = *reinterpret_cast<floatx4*>(&red2[c * 12 + 4]);
  const floatx4 SY = *reinterpret_cast<floatx4*>(&red2[c * 12 + 8]);
  floatx4 cx, cy;
#pragma unroll
  for (int i = 0; i < 4; ++i) {
    const float inv = 1.0f / (S0[i] + 1e-6f);
    cx[i] = SX[i] * inv;
    cy[i] = SY[i] * inv;
  }

  const floatx4 Xs = X - cx;
  const floatx4 Xs2 = Xs * Xs;
  const floatx4 Xs3 = Xs2 * Xs;
  const floatx4 lim = 1.0f - Xs2;   // mask: Ys^2 <= 1 - Xs^2

  // Pass 2 (from registers): m_j = sum_k g * Ys^j, j=0..3, per channel.
  floatx4 m0 = {0,0,0,0}, m1 = {0,0,0,0}, m2 = {0,0,0,0}, m3 = {0,0,0,0};
#pragma unroll
  for (int j = 0; j < 16; ++j) {
    const float Y = -1.0f + (float)j * (2.0f / 15.0f);
    const floatx4 Ys = Y - cy;
    const floatx4 Ys2 = Ys * Ys;
    floatx4 g;
#pragma unroll
    for (int i = 0; i < 4; ++i) g[i] = (Ys2[i] <= lim[i]) ? f[j][i] : 0.0f;
    const floatx4 gy = g * Ys;
    m0 += g;
    m1 += gy;
    m2 += gy * Ys;
    m3 += gy * Ys2;
  }

  // Per-thread S_ij = Xs^i * m_j partials -> LDS [16 q][960 words].
  {
    float* wp = &lds[q * 960 + c * 40];
    *reinterpret_cast<floatx4*>(wp +  0) = m0;         // S00
    *reinterpret_cast<floatx4*>(wp +  4) = Xs  * m0;   // S10
    *reinterpret_cast<floatx4*>(wp +  8) = Xs2 * m0;   // S20
    *reinterpret_cast<floatx4*>(wp + 12) = Xs3 * m0;   // S30
    *reinterpret_cast<floatx4*>(wp + 16) = m1;         // S01
    *reinterpret_cast<floatx4*>(wp + 20) = Xs  * m1;   // S11
    *reinterpret_cast<floatx4*>(wp + 24) = Xs2 * m1;   // S21
    *reinterpret_cast<floatx4*>(wp + 28) = m2;         // S02
    *reinterpret_cast<floatx4*>(wp + 32) = Xs  * m2;   // S12
    *reinterpret_cast<floatx4*>(wp + 36) = m3;         // S03
  }
  __syncthreads();
  for (int w = t; w < 960; w += 384) {
    float S = 0.f;
#pragma unroll
    for (int qq = 0; qq < 16; ++qq) S += lds[qq * 960 + w];
    red2[w] = S;
  }
  __syncthreads();

  if (t < 96) {                      // thread t = channel ch
    const int cc = t >> 2, comp = t & 3;
    const float* rp = &red2[cc * 40 + comp];
    const float S00 = rp[0],  S10 = rp[4],  S20 = rp[8],  S30 = rp[12];
    const float S01 = rp[16], S11 = rp[20], S21 = rp[24];
    const float S02 = rp[28], S12 = rp[32], S03 = rp[36];
    const float a0 = S00;
    const float a1 = S10, b1 = S01;
    const float a2 = 2.0f * (S20 + S02) - S00;
    const float a3 = S20 - S02, b3 = 2.0f * S11;
    const float a4 = 3.0f * (S30 + S12) - 2.0f * S10;
    const float b4 = 3.0f * (S21 + S03) - 2.0f * S01;
    const float a5 = S30 - 3.0f * S12;
    const float b5 = 3.0f * S21 - S03;
    const float INV = 1.0f / 65536.0f;       // (1/256)^2 for the squared means
    const int rank = t / 32, cw = t % 32;
    float* po = pooled + (size_t)b * 576 + rank * 192 + cw;
    po[0]   = (1.0f / PI_F) * sqrtf(a0 * a0 * INV + 1e-12f);
    po[32]  = (2.0f / PI_F) * sqrtf(fmaf(a1, a1, b1 * b1) * INV + 1e-12f);
    po[64]  = (3.0f / PI_F) * sqrtf(a2 * a2 * INV + 1e-12f);
    po[96]  = (3.0f / PI_F) * sqrtf(fmaf(a3, a3, b3 * b3) * INV + 1e-12f);
    po[128] = (4.0f / PI_F) * sqrtf(fmaf(a4, a4, b4 * b4) * INV + 1e-12f);
    po[160] = (4.0f / PI_F) * sqrtf(fmaf(a5, a5, b5 * b5) * INV + 1e-12f);
  }
}

// Kernel 2: BN stats, coalesced. 9 blocks x 1024 thr; block owns 64 features;
// wave w accumulates rows w, w+16, ... (64 rows); lane owns one feature.
__global__ __launch_bounds__(1024) void bn_stats_kernel(const float* __restrict__ pooled,
                                                        const float* __restrict__ gamma,
                                                        const float* __restrict__ beta,
                                                        float* __restrict__ a,
                                                        float* __restrict__ c) {
  const int f0 = blockIdx.x * 64;          // 0,64,...,512
  const int t = threadIdx.x;
  const int w = t >> 6, lane = t & 63;
  const float* p = pooled + f0 + lane;
  float s = 0.0f, sq = 0.0f;
  for (int row = w; row < 1024; row += 16) {
    const float v = p[(size_t)row * 576];  // 256B coalesced per wave-instr
    s += v;
    sq = fmaf(v, v, sq);
  }
  __shared__ float ls[16][64];
  __shared__ float lq[16][64];
  ls[w][lane] = s;
  lq[w][lane] = sq;
  __syncthreads();
  if (t < 64) {
    float S = 0.0f, Q = 0.0f;
#pragma unroll
    for (int i = 0; i < 16; ++i) { S += ls[i][t]; Q += lq[i][t]; }
    const float mean = S * (1.0f / 1024.0f);
    const float var = fmaf(-mean, mean, Q * (1.0f / 1024.0f));  // biased var
    const float istd = rsqrtf(var + 1e-5f);
    const float av = gamma[f0 + t] * istd;
    a[f0 + t] = av;
    c[f0 + t] = fmaf(-mean, av, beta[f0 + t]);
  }
}

// Kernel 3: z = pooled*a + c, then z @ W^T + b. One wave per batch row.
__global__ __launch_bounds__(64) void head_kernel(const float* __restrict__ pooled,
                                                  const float* __restrict__ a,
                                                  const float* __restrict__ c,
                                                  const float* __restrict__ Wl,
                                                  const float* __restrict__ bl,
                                                  float* __restrict__ out) {
  const int row = blockIdx.x;     // 0..1023
  const int lane = threadIdx.x;   // 0..63
  const float* pr = pooled + (size_t)row * 576;
  float acc0 = 0, acc1 = 0, acc2 = 0, acc3 = 0, acc4 = 0;
  float acc5 = 0, acc6 = 0, acc7 = 0, acc8 = 0, acc9 = 0;
#pragma unroll
  for (int j = 0; j < 9; ++j) {
    const int k = lane + 64 * j;
    const float z = fmaf(pr[k], a[k], c[k]);
    acc0 = fmaf(z, Wl[0 * 576 + k], acc0);
    acc1 = fmaf(z, Wl[1 * 576 + k], acc1);
    acc2 = fmaf(z, Wl[2 * 576 + k], acc2);
    acc3 = fmaf(z, Wl[3 * 576 + k], acc3);
    acc4 = fmaf(z, Wl[4 * 576 + k], acc4);
    acc5 = fmaf(z, Wl[5 * 576 + k], acc5);
    acc6 = fmaf(z, Wl[6 * 576 + k], acc6);
    acc7 = fmaf(z, Wl[7 * 576 + k], acc7);
    acc8 = fmaf(z, Wl[8 * 576 + k], acc8);
    acc9 = fmaf(z, Wl[9 * 576 + k], acc9);
  }
#pragma unroll
  for (int m = 1; m < 64; m <<= 1) {
    acc0 += __shfl_xor(acc0, m); acc1 += __shfl_xor(acc1, m);
    acc2 += __shfl_xor(acc2, m); acc3 += __shfl_xor(acc3, m);
    acc4 += __shfl_xor(acc4, m); acc5 += __shfl_xor(acc5, m);
    acc6 += __shfl_xor(acc6, m); acc7 += __shfl_xor(acc7, m);
    acc8 += __shfl_xor(acc8, m); acc9 += __shfl_xor(acc9, m);
  }
  if (lane == 0) {
    float* o = out + (size_t)row * 10;
    o[0] = acc0 + bl[0]; o[1] = acc1 + bl[1]; o[2] = acc2 + bl[2];
    o[3] = acc3 + bl[3]; o[4] = acc4 + bl[4]; o[5] = acc5 + bl[5];
    o[6] = acc6 + bl[6]; o[7] = acc7 + bl[7]; o[8] = acc8 + bl[8];
    o[9] = acc9 + bl[9];
  }
}

extern "C" void kernel_launch(void* const* d_in, const int* in_sizes, int n_in,
                              void* d_out, int out_size, void* d_ws, size_t ws_size,
                              hipStream_t stream) {
  const float* x     = (const float*)d_in[0];
  const float* gamma = (const float*)d_in[1];
  const float* beta  = (const float*)d_in[2];
  const float* Wl    = (const float*)d_in[3];
  const float* bl    = (const float*)d_in[4];
  float* out = (float*)d_out;

  float* pooled = (float*)d_ws;            // 1024*576 floats
  float* a = pooled + 576 * 1024;          // 576 floats
  float* c = a + 576;                      // 576 floats

  zpool_kernel<<<1024, 384, 0, stream>>>(x, pooled);
  bn_stats_kernel<<<9, 1024, 0, stream>>>(pooled, gamma, beta, a, c);
  head_kernel<<<1024, 64, 0, stream>>>(pooled, a, c, Wl, bl, out);
}

// Round 9
// 55.509 us; speedup vs baseline: 1.1080x; 1.1080x over previous
//
#include <hip/hip_runtime.h>
#include <math.h>

#define PI_F 3.14159265358979323846f
#define LSTR 266   // 256 + 10; stride%32 == 10 -> ~2-way bank aliasing (free)

// ---- 16-lane sum reduction entirely on the VALU pipe via DPP ----
// (validated on HW in rounds 7/8: absmax 0.0039 passed with this reduce)
template <int CTRL>
__device__ __forceinline__ float dpp_addf(float v) {
  int p = __builtin_amdgcn_update_dpp(0, __float_as_int(v), CTRL, 0xF, 0xF, true);
  return v + __int_as_float(p);
}
__device__ __forceinline__ float red16(float v) {
  v = dpp_addf<0xB1>(v);    // quad_perm [1,0,3,2]  (xor 1)
  v = dpp_addf<0x4E>(v);    // quad_perm [2,3,0,1]  (xor 2)
  v = dpp_addf<0x124>(v);   // row_ror:4
  v = dpp_addf<0x128>(v);   // row_ror:8
  return v;
}

// Kernel 1: Zernike pooling. One block per (batch, rank): 32 channels x 256 pixels.
// Identical to the round-2 best (44.1us total) EXCEPT reductions are DPP (VALU
// pipe) instead of __shfl_xor (LDS pipe): LDS-pipe ops/thread 152 -> 48.
__global__ __launch_bounds__(256) void zpool_kernel(const float* __restrict__ x,
                                                    float* __restrict__ pooled) {
  const int blk = blockIdx.x;              // 0..3071
  const int b = blk / 3;
  const int rank = blk - b * 3;
  const float* __restrict__ src = x + (size_t)b * 24576 + rank * 32;

  __shared__ float lds[32 * LSTR];
  const int t = threadIdx.x;

  // Stage tile: 256 rows x 32 ch. float4 global loads (full 64B lines),
  // 4 scalar LDS writes each (transpose to channel-major).
#pragma unroll
  for (int i = 0; i < 8; ++i) {
    const int idx = t + i * 256;           // 0..2047
    const int p = idx >> 3;                // pixel 0..255
    const int c4 = (idx & 7) * 4;          // channel base 0..28
    const float4 v = *reinterpret_cast<const float4*>(src + p * 96 + c4);
    lds[(c4 + 0) * LSTR + p] = v.x;
    lds[(c4 + 1) * LSTR + p] = v.y;
    lds[(c4 + 2) * LSTR + p] = v.z;
    lds[(c4 + 3) * LSTR + p] = v.w;
  }
  __syncthreads();

  const int lane = t & 63;
  const int w = t >> 6;                    // wave 0..3
  const int sub = lane >> 4;               // channel subgroup 0..3
  const int sl = lane & 15;                // pixel column (w-coord)
  const float X = -1.0f + (float)sl * (2.0f / 15.0f);   // lane-constant

#pragma unroll
  for (int g = 0; g < 2; ++g) {
    const int ch = w * 8 + g * 4 + sub;    // 0..31
    const float* base = &lds[ch * LSTR + sl];
    float f[16];
#pragma unroll
    for (int k = 0; k < 16; ++k) f[k] = base[16 * k];   // pixel p = sl + 16k

    // Pass 1: centroid sums. X constant per lane -> sx = X * s0.
    float s0 = 0.0f, sy = 0.0f;
#pragma unroll
    for (int k = 0; k < 16; ++k) {
      const float Y = -1.0f + (float)k * (2.0f / 15.0f);
      s0 += f[k];
      sy = fmaf(f[k], Y, sy);
    }
    float sx = X * s0;
    s0 = red16(s0); sx = red16(sx); sy = red16(sy);
    const float invm = 1.0f / (s0 + 1e-6f);
    const float cx = sx * invm;
    const float cy = sy * invm;

    const float Xs = X - cx;
    const float Xs2 = Xs * Xs;
    const float twoXs = Xs + Xs;
    const float thXs2 = 3.0f * Xs2;

    // Pass 2: polynomial moment accumulators (re/im pairs, im sign dropped).
    float a0 = 0, a1 = 0, b1 = 0, a2 = 0, a3 = 0, b3 = 0, a4 = 0, b4 = 0, a5 = 0, b5 = 0;
#pragma unroll
    for (int k = 0; k < 16; ++k) {
      const float Y = -1.0f + (float)k * (2.0f / 15.0f);
      const float Ys = Y - cy;
      const float Ys2 = Ys * Ys;
      const float r2 = Xs2 + Ys2;
      const float gv = (r2 <= 1.0f) ? f[k] : 0.0f;   // unit-disk mask
      const float gx = gv * Xs;
      const float gy = gv * Ys;
      a0 += gv;
      a1 += gx;
      b1 += gy;
      a2 = fmaf(gv, fmaf(2.0f, r2, -1.0f), a2);
      a3 = fmaf(gv, Xs2 - Ys2, a3);
      b3 = fmaf(gy, twoXs, b3);
      const float t31 = fmaf(3.0f, r2, -2.0f);
      a4 = fmaf(gx, t31, a4);
      b4 = fmaf(gy, t31, b4);
      a5 = fmaf(gx, fmaf(-3.0f, Ys2, Xs2), a5);
      b5 = fmaf(gy, thXs2 - Ys2, b5);
    }
    a0 = red16(a0); a1 = red16(a1); b1 = red16(b1); a2 = red16(a2); a3 = red16(a3);
    b3 = red16(b3); a4 = red16(a4); b4 = red16(b4); a5 = red16(a5); b5 = red16(b5);

    if (sl == 0) {
      float* po = pooled + (size_t)b * 576 + rank * 192 + ch;
      const float INV = 1.0f / 65536.0f;    // (1/256)^2 for the means
      po[0]   = (1.0f / PI_F) * sqrtf(a0 * a0 * INV + 1e-12f);
      po[32]  = (2.0f / PI_F) * sqrtf(fmaf(a1, a1, b1 * b1) * INV + 1e-12f);
      po[64]  = (3.0f / PI_F) * sqrtf(a2 * a2 * INV + 1e-12f);
      po[96]  = (3.0f / PI_F) * sqrtf(fmaf(a3, a3, b3 * b3) * INV + 1e-12f);
      po[128] = (4.0f / PI_F) * sqrtf(fmaf(a4, a4, b4 * b4) * INV + 1e-12f);
      po[160] = (4.0f / PI_F) * sqrtf(fmaf(a5, a5, b5 * b5) * INV + 1e-12f);
    }
  }
}

// Kernel 2: BN stats, coalesced. 9 blocks x 1024 thr; block owns 64 features;
// wave w accumulates rows w, w+16, ... (64 rows); lane owns one feature.
// (validated correct in rounds 6-8)
__global__ __launch_bounds__(1024) void bn_stats_kernel(const float* __restrict__ pooled,
                                                        const float* __restrict__ gamma,
                                                        const float* __restrict__ beta,
                                                        float* __restrict__ a,
                                                        float* __restrict__ c) {
  const int f0 = blockIdx.x * 64;          // 0,64,...,512
  const int t = threadIdx.x;
  const int w = t >> 6, lane = t & 63;
  const float* p = pooled + f0 + lane;
  float s = 0.0f, sq = 0.0f;
  for (int row = w; row < 1024; row += 16) {
    const float v = p[(size_t)row * 576];  // 256B coalesced per wave-instr
    s += v;
    sq = fmaf(v, v, sq);
  }
  __shared__ float ls[16][64];
  __shared__ float lq[16][64];
  ls[w][lane] = s;
  lq[w][lane] = sq;
  __syncthreads();
  if (t < 64) {
    float S = 0.0f, Q = 0.0f;
#pragma unroll
    for (int i = 0; i < 16; ++i) { S += ls[i][t]; Q += lq[i][t]; }
    const float mean = S * (1.0f / 1024.0f);
    const float var = fmaf(-mean, mean, Q * (1.0f / 1024.0f));  // biased var
    const float istd = rsqrtf(var + 1e-5f);
    const float av = gamma[f0 + t] * istd;
    a[f0 + t] = av;
    c[f0 + t] = fmaf(-mean, av, beta[f0 + t]);
  }
}

// Kernel 3: z = pooled*a + c, then z @ W^T + b. One wave per batch row.
__global__ __launch_bounds__(64) void head_kernel(const float* __restrict__ pooled,
                                                  const float* __restrict__ a,
                                                  const float* __restrict__ c,
                                                  const float* __restrict__ Wl,
                                                  const float* __restrict__ bl,
                                                  float* __restrict__ out) {
  const int row = blockIdx.x;     // 0..1023
  const int lane = threadIdx.x;   // 0..63
  const float* pr = pooled + (size_t)row * 576;
  float acc0 = 0, acc1 = 0, acc2 = 0, acc3 = 0, acc4 = 0;
  float acc5 = 0, acc6 = 0, acc7 = 0, acc8 = 0, acc9 = 0;
#pragma unroll
  for (int j = 0; j < 9; ++j) {
    const int k = lane + 64 * j;
    const float z = fmaf(pr[k], a[k], c[k]);
    acc0 = fmaf(z, Wl[0 * 576 + k], acc0);
    acc1 = fmaf(z, Wl[1 * 576 + k], acc1);
    acc2 = fmaf(z, Wl[2 * 576 + k], acc2);
    acc3 = fmaf(z, Wl[3 * 576 + k], acc3);
    acc4 = fmaf(z, Wl[4 * 576 + k], acc4);
    acc5 = fmaf(z, Wl[5 * 576 + k], acc5);
    acc6 = fmaf(z, Wl[6 * 576 + k], acc6);
    acc7 = fmaf(z, Wl[7 * 576 + k], acc7);
    acc8 = fmaf(z, Wl[8 * 576 + k], acc8);
    acc9 = fmaf(z, Wl[9 * 576 + k], acc9);
  }
#pragma unroll
  for (int m = 1; m < 64; m <<= 1) {
    acc0 += __shfl_xor(acc0, m); acc1 += __shfl_xor(acc1, m);
    acc2 += __shfl_xor(acc2, m); acc3 += __shfl_xor(acc3, m);
    acc4 += __shfl_xor(acc4, m); acc5 += __shfl_xor(acc5, m);
    acc6 += __shfl_xor(acc6, m); acc7 += __shfl_xor(acc7, m);
    acc8 += __shfl_xor(acc8, m); acc9 += __shfl_xor(acc9, m);
  }
  if (lane == 0) {
    float* o = out + (size_t)row * 10;
    o[0] = acc0 + bl[0]; o[1] = acc1 + bl[1]; o[2] = acc2 + bl[2];
    o[3] = acc3 + bl[3]; o[4] = acc4 + bl[4]; o[5] = acc5 + bl[5];
    o[6] = acc6 + bl[6]; o[7] = acc7 + bl[7]; o[8] = acc8 + bl[8];
    o[9] = acc9 + bl[9];
  }
}

extern "C" void kernel_launch(void* const* d_in, const int* in_sizes, int n_in,
                              void* d_out, int out_size, void* d_ws, size_t ws_size,
                              hipStream_t stream) {
  const float* x     = (const float*)d_in[0];
  const float* gamma = (const float*)d_in[1];
  const float* beta  = (const float*)d_in[2];
  const float* Wl    = (const float*)d_in[3];
  const float* bl    = (const float*)d_in[4];
  float* out = (float*)d_out;

  float* pooled = (float*)d_ws;            // 1024*576 floats
  float* a = pooled + 576 * 1024;          // 576 floats
  float* c = a + 576;                      // 576 floats

  zpool_kernel<<<3072, 256, 0, stream>>>(x, pooled);
  bn_stats_kernel<<<9, 1024, 0, stream>>>(pooled, gamma, beta, a, c);
  head_kernel<<<1024, 64, 0, stream>>>(pooled, a, c, Wl, bl, out);
}

// Round 10
// 40.294 us; speedup vs baseline: 1.5263x; 1.3776x over previous
//
#include <hip/hip_runtime.h>
#include <math.h>

#define PI_F 3.14159265358979323846f
#define LSTR 266   // 256 + 10; stride%32 == 10 -> ~2-way bank aliasing (free)

__device__ __forceinline__ float red16(float v) {
  v += __shfl_xor(v, 1);
  v += __shfl_xor(v, 2);
  v += __shfl_xor(v, 4);
  v += __shfl_xor(v, 8);
  return v;
}

// Kernel 1: Zernike pooling. One block per (batch, rank): 32 channels x 256 pixels.
// Identical to the round-2 best (44.1us) EXCEPT pass 2 uses the 4-moment algebra
// (m_j = sum g*Ys^j; S_ij = Xs^i * m_j derived after the loop): ~21 -> ~8
// VALU/pixel, reduction count unchanged (13 values/channel).
__global__ __launch_bounds__(256) void zpool_kernel(const float* __restrict__ x,
                                                    float* __restrict__ pooled) {
  const int blk = blockIdx.x;              // 0..3071
  const int b = blk / 3;
  const int rank = blk - b * 3;
  const float* __restrict__ src = x + (size_t)b * 24576 + rank * 32;

  __shared__ float lds[32 * LSTR];
  const int t = threadIdx.x;

  // Stage tile: 256 rows x 32 ch. float4 global loads (full 64B lines),
  // 4 scalar LDS writes each (transpose to channel-major).
#pragma unroll
  for (int i = 0; i < 8; ++i) {
    const int idx = t + i * 256;           // 0..2047
    const int p = idx >> 3;                // pixel 0..255
    const int c4 = (idx & 7) * 4;          // channel base 0..28
    const float4 v = *reinterpret_cast<const float4*>(src + p * 96 + c4);
    lds[(c4 + 0) * LSTR + p] = v.x;
    lds[(c4 + 1) * LSTR + p] = v.y;
    lds[(c4 + 2) * LSTR + p] = v.z;
    lds[(c4 + 3) * LSTR + p] = v.w;
  }
  __syncthreads();

  const int lane = t & 63;
  const int w = t >> 6;                    // wave 0..3
  const int sub = lane >> 4;               // channel subgroup 0..3
  const int sl = lane & 15;                // pixel column (w-coord)
  const float X = -1.0f + (float)sl * (2.0f / 15.0f);   // lane-constant

#pragma unroll
  for (int g = 0; g < 2; ++g) {
    const int ch = w * 8 + g * 4 + sub;    // 0..31
    const float* base = &lds[ch * LSTR + sl];
    float f[16];
#pragma unroll
    for (int k = 0; k < 16; ++k) f[k] = base[16 * k];   // pixel p = sl + 16k

    // Pass 1: centroid sums. X constant per lane -> sx = X * s0.
    float s0 = 0.0f, sy = 0.0f;
#pragma unroll
    for (int k = 0; k < 16; ++k) {
      const float Y = -1.0f + (float)k * (2.0f / 15.0f);
      s0 += f[k];
      sy = fmaf(f[k], Y, sy);
    }
    float sx = X * s0;
    s0 = red16(s0); sx = red16(sx); sy = red16(sy);
    const float invm = 1.0f / (s0 + 1e-6f);
    const float cx = sx * invm;
    const float cy = sy * invm;

    const float Xs = X - cx;
    const float Xs2 = Xs * Xs;
    const float Xs3 = Xs2 * Xs;
    const float lim = 1.0f - Xs2;          // mask: Ys^2 <= 1 - Xs^2  (== r2 <= 1)

    // Pass 2: 4 moment accumulators m_j = sum g * Ys^j  (validated R7/R8).
    float m0 = 0.0f, m1 = 0.0f, m2 = 0.0f, m3 = 0.0f;
#pragma unroll
    for (int k = 0; k < 16; ++k) {
      const float Y = -1.0f + (float)k * (2.0f / 15.0f);
      const float Ys = Y - cy;
      const float Ys2 = Ys * Ys;
      const float gv = (Ys2 <= lim) ? f[k] : 0.0f;
      const float gy = gv * Ys;
      m0 += gv;
      m1 += gy;
      m2 = fmaf(gy, Ys, m2);
      m3 = fmaf(gy, Ys2, m3);
    }

    // Derive the 10 raw sums S_ij = Xs^i * m_j (lane-local; Xs lane-constant).
    float S00 = m0;
    float S10 = Xs * m0;
    float S20 = Xs2 * m0;
    float S30 = Xs3 * m0;
    float S01 = m1;
    float S11 = Xs * m1;
    float S21 = Xs2 * m1;
    float S02 = m2;
    float S12 = Xs * m2;
    float S03 = m3;

    S00 = red16(S00); S10 = red16(S10); S20 = red16(S20); S30 = red16(S30);
    S01 = red16(S01); S11 = red16(S11); S21 = red16(S21);
    S02 = red16(S02); S12 = red16(S12); S03 = red16(S03);

    if (sl == 0) {
      const float a0 = S00;
      const float a1 = S10, b1 = S01;
      const float a2 = 2.0f * (S20 + S02) - S00;
      const float a3 = S20 - S02, b3 = 2.0f * S11;
      const float a4 = 3.0f * (S30 + S12) - 2.0f * S10;
      const float b4 = 3.0f * (S21 + S03) - 2.0f * S01;
      const float a5 = S30 - 3.0f * S12;
      const float b5 = 3.0f * S21 - S03;
      float* po = pooled + (size_t)b * 576 + rank * 192 + ch;
      const float INV = 1.0f / 65536.0f;    // (1/256)^2 for the means
      po[0]   = (1.0f / PI_F) * sqrtf(a0 * a0 * INV + 1e-12f);
      po[32]  = (2.0f / PI_F) * sqrtf(fmaf(a1, a1, b1 * b1) * INV + 1e-12f);
      po[64]  = (3.0f / PI_F) * sqrtf(a2 * a2 * INV + 1e-12f);
      po[96]  = (3.0f / PI_F) * sqrtf(fmaf(a3, a3, b3 * b3) * INV + 1e-12f);
      po[128] = (4.0f / PI_F) * sqrtf(fmaf(a4, a4, b4 * b4) * INV + 1e-12f);
      po[160] = (4.0f / PI_F) * sqrtf(fmaf(a5, a5, b5 * b5) * INV + 1e-12f);
    }
  }
}

// Kernel 2: batch-norm stats per feature; fold into scale a and shift c.
// (byte-identical to the round-2 44.1us package)
__global__ __launch_bounds__(256) void bn_stats_kernel(const float* __restrict__ pooled,
                                                       const float* __restrict__ gamma,
                                                       const float* __restrict__ beta,
                                                       float* __restrict__ a,
                                                       float* __restrict__ c) {
  const int f = blockIdx.x;   // 0..575
  const int t = threadIdx.x;  // 256
  float s = 0.0f, sq = 0.0f;
#pragma unroll
  for (int j = 0; j < 4; ++j) {
    const float v = pooled[(size_t)(t + 256 * j) * 576 + f];
    s += v;
    sq = fmaf(v, v, sq);
  }
#pragma unroll
  for (int m = 1; m < 64; m <<= 1) {
    s += __shfl_xor(s, m);
    sq += __shfl_xor(sq, m);
  }
  __shared__ float ls[8];
  const int w = t >> 6;
  if ((t & 63) == 0) { ls[w * 2] = s; ls[w * 2 + 1] = sq; }
  __syncthreads();
  if (t == 0) {
    s = ls[0] + ls[2] + ls[4] + ls[6];
    sq = ls[1] + ls[3] + ls[5] + ls[7];
    const float mean = s * (1.0f / 1024.0f);
    const float var = fmaf(-mean, mean, sq * (1.0f / 1024.0f));  // biased var
    const float istd = rsqrtf(var + 1e-5f);
    const float av = gamma[f] * istd;
    a[f] = av;
    c[f] = fmaf(-mean, av, beta[f]);
  }
}

// Kernel 3: z = pooled*a + c, then z @ W^T + b. One wave per batch row.
__global__ __launch_bounds__(64) void head_kernel(const float* __restrict__ pooled,
                                                  const float* __restrict__ a,
                                                  const float* __restrict__ c,
                                                  const float* __restrict__ Wl,
                                                  const float* __restrict__ bl,
                                                  float* __restrict__ out) {
  const int row = blockIdx.x;     // 0..1023
  const int lane = threadIdx.x;   // 0..63
  const float* pr = pooled + (size_t)row * 576;
  float acc0 = 0, acc1 = 0, acc2 = 0, acc3 = 0, acc4 = 0;
  float acc5 = 0, acc6 = 0, acc7 = 0, acc8 = 0, acc9 = 0;
#pragma unroll
  for (int j = 0; j < 9; ++j) {
    const int k = lane + 64 * j;
    const float z = fmaf(pr[k], a[k], c[k]);
    acc0 = fmaf(z, Wl[0 * 576 + k], acc0);
    acc1 = fmaf(z, Wl[1 * 576 + k], acc1);
    acc2 = fmaf(z, Wl[2 * 576 + k], acc2);
    acc3 = fmaf(z, Wl[3 * 576 + k], acc3);
    acc4 = fmaf(z, Wl[4 * 576 + k], acc4);
    acc5 = fmaf(z, Wl[5 * 576 + k], acc5);
    acc6 = fmaf(z, Wl[6 * 576 + k], acc6);
    acc7 = fmaf(z, Wl[7 * 576 + k], acc7);
    acc8 = fmaf(z, Wl[8 * 576 + k], acc8);
    acc9 = fmaf(z, Wl[9 * 576 + k], acc9);
  }
#pragma unroll
  for (int m = 1; m < 64; m <<= 1) {
    acc0 += __shfl_xor(acc0, m); acc1 += __shfl_xor(acc1, m);
    acc2 += __shfl_xor(acc2, m); acc3 += __shfl_xor(acc3, m);
    acc4 += __shfl_xor(acc4, m); acc5 += __shfl_xor(acc5, m);
    acc6 += __shfl_xor(acc6, m); acc7 += __shfl_xor(acc7, m);
    acc8 += __shfl_xor(acc8, m); acc9 += __shfl_xor(acc9, m);
  }
  if (lane == 0) {
    float* o = out + (size_t)row * 10;
    o[0] = acc0 + bl[0]; o[1] = acc1 + bl[1]; o[2] = acc2 + bl[2];
    o[3] = acc3 + bl[3]; o[4] = acc4 + bl[4]; o[5] = acc5 + bl[5];
    o[6] = acc6 + bl[6]; o[7] = acc7 + bl[7]; o[8] = acc8 + bl[8];
    o[9] = acc9 + bl[9];
  }
}

extern "C" void kernel_launch(void* const* d_in, const int* in_sizes, int n_in,
                              void* d_out, int out_size, void* d_ws, size_t ws_size,
                              hipStream_t stream) {
  const float* x     = (const float*)d_in[0];
  const float* gamma = (const float*)d_in[1];
  const float* beta  = (const float*)d_in[2];
  const float* Wl    = (const float*)d_in[3];
  const float* bl    = (const float*)d_in[4];
  float* out = (float*)d_out;

  float* pooled = (float*)d_ws;            // 1024*576 floats
  float* a = pooled + 576 * 1024;          // 576 floats
  float* c = a + 576;                      // 576 floats

  zpool_kernel<<<3072, 256, 0, stream>>>(x, pooled);
  bn_stats_kernel<<<576, 256, 0, stream>>>(pooled, gamma, beta, a, c);
  head_kernel<<<1024, 64, 0, stream>>>(pooled, a, c, Wl, bl, out);
}

// Round 11
// 36.183 us; speedup vs baseline: 1.6997x; 1.1136x over previous
//
#include <hip/hip_runtime.h>
#include <math.h>

#define PI_F 3.14159265358979323846f
#define LSTR 266   // 256 + 10; stride%32 == 10 -> ~2-way bank aliasing (free)

// ---- 16-lane sum reduction entirely on the VALU pipe via DPP ----
// quad_perm xor1 (0xB1), quad_perm xor2 (0x4E), row_ror:4 (0x124), row_ror:8
// (0x128). DPP rows = lanes [16s..16s+15] align exactly with our subgroups.
// Numerics HW-validated in rounds 7/8 (absmax 0.0039 passed).
template <int CTRL>
__device__ __forceinline__ float dpp_addf(float v) {
  int p = __builtin_amdgcn_update_dpp(0, __float_as_int(v), CTRL, 0xF, 0xF, true);
  return v + __int_as_float(p);
}
__device__ __forceinline__ float red16(float v) {
  v = dpp_addf<0xB1>(v);
  v = dpp_addf<0x4E>(v);
  v = dpp_addf<0x124>(v);
  v = dpp_addf<0x128>(v);
  return v;
}

// Kernel 1: Zernike pooling. One block per (batch, rank): 32 channels x 256 px.
// = round-10 best (40.3us) EXCEPT red16 is DPP (VALU pipe) instead of
// __shfl_xor (LDS pipe): LDS-pipe instrs/wave 168 -> 64.
__global__ __launch_bounds__(256) void zpool_kernel(const float* __restrict__ x,
                                                    float* __restrict__ pooled) {
  const int blk = blockIdx.x;              // 0..3071
  const int b = blk / 3;
  const int rank = blk - b * 3;
  const float* __restrict__ src = x + (size_t)b * 24576 + rank * 32;

  __shared__ float lds[32 * LSTR];
  const int t = threadIdx.x;

  // Stage tile: 256 rows x 32 ch. float4 global loads (full 64B lines),
  // 4 scalar LDS writes each (transpose to channel-major).
#pragma unroll
  for (int i = 0; i < 8; ++i) {
    const int idx = t + i * 256;           // 0..2047
    const int p = idx >> 3;                // pixel 0..255
    const int c4 = (idx & 7) * 4;          // channel base 0..28
    const float4 v = *reinterpret_cast<const float4*>(src + p * 96 + c4);
    lds[(c4 + 0) * LSTR + p] = v.x;
    lds[(c4 + 1) * LSTR + p] = v.y;
    lds[(c4 + 2) * LSTR + p] = v.z;
    lds[(c4 + 3) * LSTR + p] = v.w;
  }
  __syncthreads();

  const int lane = t & 63;
  const int w = t >> 6;                    // wave 0..3
  const int sub = lane >> 4;               // channel subgroup 0..3
  const int sl = lane & 15;                // pixel column (w-coord)
  const float X = -1.0f + (float)sl * (2.0f / 15.0f);   // lane-constant

#pragma unroll
  for (int g = 0; g < 2; ++g) {
    const int ch = w * 8 + g * 4 + sub;    // 0..31
    const float* base = &lds[ch * LSTR + sl];
    float f[16];
#pragma unroll
    for (int k = 0; k < 16; ++k) f[k] = base[16 * k];   // pixel p = sl + 16k

    // Pass 1: centroid sums. X constant per lane -> sx = X * s0.
    float s0 = 0.0f, sy = 0.0f;
#pragma unroll
    for (int k = 0; k < 16; ++k) {
      const float Y = -1.0f + (float)k * (2.0f / 15.0f);
      s0 += f[k];
      sy = fmaf(f[k], Y, sy);
    }
    float sx = X * s0;
    s0 = red16(s0); sx = red16(sx); sy = red16(sy);
    const float invm = 1.0f / (s0 + 1e-6f);
    const float cx = sx * invm;
    const float cy = sy * invm;

    const float Xs = X - cx;
    const float Xs2 = Xs * Xs;
    const float Xs3 = Xs2 * Xs;
    const float lim = 1.0f - Xs2;          // mask: Ys^2 <= 1 - Xs^2  (== r2 <= 1)

    // Pass 2: 4 moment accumulators m_j = sum g * Ys^j  (validated R7/R8/R10).
    float m0 = 0.0f, m1 = 0.0f, m2 = 0.0f, m3 = 0.0f;
#pragma unroll
    for (int k = 0; k < 16; ++k) {
      const float Y = -1.0f + (float)k * (2.0f / 15.0f);
      const float Ys = Y - cy;
      const float Ys2 = Ys * Ys;
      const float gv = (Ys2 <= lim) ? f[k] : 0.0f;
      const float gy = gv * Ys;
      m0 += gv;
      m1 += gy;
      m2 = fmaf(gy, Ys, m2);
      m3 = fmaf(gy, Ys2, m3);
    }

    // Derive the 10 raw sums S_ij = Xs^i * m_j (lane-local; Xs lane-constant).
    float S00 = m0;
    float S10 = Xs * m0;
    float S20 = Xs2 * m0;
    float S30 = Xs3 * m0;
    float S01 = m1;
    float S11 = Xs * m1;
    float S21 = Xs2 * m1;
    float S02 = m2;
    float S12 = Xs * m2;
    float S03 = m3;

    S00 = red16(S00); S10 = red16(S10); S20 = red16(S20); S30 = red16(S30);
    S01 = red16(S01); S11 = red16(S11); S21 = red16(S21);
    S02 = red16(S02); S12 = red16(S12); S03 = red16(S03);

    if (sl == 0) {
      const float a0 = S00;
      const float a1 = S10, b1 = S01;
      const float a2 = 2.0f * (S20 + S02) - S00;
      const float a3 = S20 - S02, b3 = 2.0f * S11;
      const float a4 = 3.0f * (S30 + S12) - 2.0f * S10;
      const float b4 = 3.0f * (S21 + S03) - 2.0f * S01;
      const float a5 = S30 - 3.0f * S12;
      const float b5 = 3.0f * S21 - S03;
      float* po = pooled + (size_t)b * 576 + rank * 192 + ch;
      const float INV = 1.0f / 65536.0f;    // (1/256)^2 for the means
      po[0]   = (1.0f / PI_F) * sqrtf(a0 * a0 * INV + 1e-12f);
      po[32]  = (2.0f / PI_F) * sqrtf(fmaf(a1, a1, b1 * b1) * INV + 1e-12f);
      po[64]  = (3.0f / PI_F) * sqrtf(a2 * a2 * INV + 1e-12f);
      po[96]  = (3.0f / PI_F) * sqrtf(fmaf(a3, a3, b3 * b3) * INV + 1e-12f);
      po[128] = (4.0f / PI_F) * sqrtf(fmaf(a4, a4, b4 * b4) * INV + 1e-12f);
      po[160] = (4.0f / PI_F) * sqrtf(fmaf(a5, a5, b5 * b5) * INV + 1e-12f);
    }
  }
}

// Kernel 2: batch-norm stats per feature; fold into scale a and shift c.
// (576-block version -- part of both winning packages R2/R10; do NOT swap)
__global__ __launch_bounds__(256) void bn_stats_kernel(const float* __restrict__ pooled,
                                                       const float* __restrict__ gamma,
                                                       const float* __restrict__ beta,
                                                       float* __restrict__ a,
                                                       float* __restrict__ c) {
  const int f = blockIdx.x;   // 0..575
  const int t = threadIdx.x;  // 256
  float s = 0.0f, sq = 0.0f;
#pragma unroll
  for (int j = 0; j < 4; ++j) {
    const float v = pooled[(size_t)(t + 256 * j) * 576 + f];
    s += v;
    sq = fmaf(v, v, sq);
  }
#pragma unroll
  for (int m = 1; m < 64; m <<= 1) {
    s += __shfl_xor(s, m);
    sq += __shfl_xor(sq, m);
  }
  __shared__ float ls[8];
  const int w = t >> 6;
  if ((t & 63) == 0) { ls[w * 2] = s; ls[w * 2 + 1] = sq; }
  __syncthreads();
  if (t == 0) {
    s = ls[0] + ls[2] + ls[4] + ls[6];
    sq = ls[1] + ls[3] + ls[5] + ls[7];
    const float mean = s * (1.0f / 1024.0f);
    const float var = fmaf(-mean, mean, sq * (1.0f / 1024.0f));  // biased var
    const float istd = rsqrtf(var + 1e-5f);
    const float av = gamma[f] * istd;
    a[f] = av;
    c[f] = fmaf(-mean, av, beta[f]);
  }
}

// Kernel 3: z = pooled*a + c, then z @ W^T + b. One wave per batch row.
__global__ __launch_bounds__(64) void head_kernel(const float* __restrict__ pooled,
                                                  const float* __restrict__ a,
                                                  const float* __restrict__ c,
                                                  const float* __restrict__ Wl,
                                                  const float* __restrict__ bl,
                                                  float* __restrict__ out) {
  const int row = blockIdx.x;     // 0..1023
  const int lane = threadIdx.x;   // 0..63
  const float* pr = pooled + (size_t)row * 576;
  float acc0 = 0, acc1 = 0, acc2 = 0, acc3 = 0, acc4 = 0;
  float acc5 = 0, acc6 = 0, acc7 = 0, acc8 = 0, acc9 = 0;
#pragma unroll
  for (int j = 0; j < 9; ++j) {
    const int k = lane + 64 * j;
    const float z = fmaf(pr[k], a[k], c[k]);
    acc0 = fmaf(z, Wl[0 * 576 + k], acc0);
    acc1 = fmaf(z, Wl[1 * 576 + k], acc1);
    acc2 = fmaf(z, Wl[2 * 576 + k], acc2);
    acc3 = fmaf(z, Wl[3 * 576 + k], acc3);
    acc4 = fmaf(z, Wl[4 * 576 + k], acc4);
    acc5 = fmaf(z, Wl[5 * 576 + k], acc5);
    acc6 = fmaf(z, Wl[6 * 576 + k], acc6);
    acc7 = fmaf(z, Wl[7 * 576 + k], acc7);
    acc8 = fmaf(z, Wl[8 * 576 + k], acc8);
    acc9 = fmaf(z, Wl[9 * 576 + k], acc9);
  }
#pragma unroll
  for (int m = 1; m < 64; m <<= 1) {
    acc0 += __shfl_xor(acc0, m); acc1 += __shfl_xor(acc1, m);
    acc2 += __shfl_xor(acc2, m); acc3 += __shfl_xor(acc3, m);
    acc4 += __shfl_xor(acc4, m); acc5 += __shfl_xor(acc5, m);
    acc6 += __shfl_xor(acc6, m); acc7 += __shfl_xor(acc7, m);
    acc8 += __shfl_xor(acc8, m); acc9 += __shfl_xor(acc9, m);
  }
  if (lane == 0) {
    float* o = out + (size_t)row * 10;
    o[0] = acc0 + bl[0]; o[1] = acc1 + bl[1]; o[2] = acc2 + bl[2];
    o[3] = acc3 + bl[3]; o[4] = acc4 + bl[4]; o[5] = acc5 + bl[5];
    o[6] = acc6 + bl[6]; o[7] = acc7 + bl[7]; o[8] = acc8 + bl[8];
    o[9] = acc9 + bl[9];
  }
}

extern "C" void kernel_launch(void* const* d_in, const int* in_sizes, int n_in,
                              void* d_out, int out_size, void* d_ws, size_t ws_size,
                              hipStream_t stream) {
  const float* x     = (const float*)d_in[0];
  const float* gamma = (const float*)d_in[1];
  const float* beta  = (const float*)d_in[2];
  const float* Wl    = (const float*)d_in[3];
  const float* bl    = (const float*)d_in[4];
  float* out = (float*)d_out;

  float* pooled = (float*)d_ws;            // 1024*576 floats
  float* a = pooled + 576 * 1024;          // 576 floats
  float* c = a + 576;                      // 576 floats

  zpool_kernel<<<3072, 256, 0, stream>>>(x, pooled);
  bn_stats_kernel<<<576, 256, 0, stream>>>(pooled, gamma, beta, a, c);
  head_kernel<<<1024, 64, 0, stream>>>(pooled, a, c, Wl, bl, out);
}